// Round 1
// baseline (1653.395 us; speedup 1.0000x reference)
//
#include <hip/hip_runtime.h>
#include <hip/hip_bf16.h>
#include <math.h>

#define B_ 64
#define L_ 1024
#define D_ 256
#define C_ 128
#define LPMAX 1536
#define K1 2304   // 9 taps * 256
#define K2 1152   // 9 taps * 128

typedef __bf16 bf16x8 __attribute__((ext_vector_type(8)));
typedef float f32x4 __attribute__((ext_vector_type(4)));

__device__ __forceinline__ unsigned short f2bf(float f) {
    __hip_bfloat16 h = __float2bfloat16(f);
    return __builtin_bit_cast(unsigned short, h);
}

__device__ __forceinline__ bf16x8 ldg_bf16x8(const unsigned short* p) {
    uint4 u = *reinterpret_cast<const uint4*>(p);
    return __builtin_bit_cast(bf16x8, u);
}

__device__ __forceinline__ bf16x8 zero_bf16x8() {
    uint4 z = {0u, 0u, 0u, 0u};
    return __builtin_bit_cast(bf16x8, z);
}

__device__ __forceinline__ float gelu_exact(float f) {
    return 0.5f * f * (1.0f + erff(f * 0.70710678118654752440f));
}

// ---- 1. cast x to bf16 + channel-mean series ----
__global__ void prep_kernel(const float* __restrict__ x, unsigned short* __restrict__ xb,
                            float* __restrict__ series) {
    int row = blockIdx.x * 4 + (threadIdx.x >> 6);
    int lane = threadIdx.x & 63;
    size_t base = (size_t)row * D_ + lane * 4;
    float4 v = *reinterpret_cast<const float4*>(x + base);
    ushort4 o;
    o.x = f2bf(v.x); o.y = f2bf(v.y); o.z = f2bf(v.z); o.w = f2bf(v.w);
    *reinterpret_cast<ushort4*>(xb + base) = o;
    float s = v.x + v.y + v.z + v.w;
    #pragma unroll
    for (int d = 32; d; d >>= 1) s += __shfl_xor(s, d);
    if (lane == 0) series[row] = s * (1.0f / D_);
}

// ---- 2. twiddle table (double) ----
__global__ void tw_kernel(double* __restrict__ tw) {
    int j = blockIdx.x * 256 + threadIdx.x;
    if (j < 1024) {
        double a = -2.0 * 3.14159265358979323846 * (double)j / 1024.0;
        tw[2 * j] = cos(a);
        tw[2 * j + 1] = sin(a);
    }
}

// ---- 3. repack weights to bf16 GEMM layout ----
// W1r[c][tap*256+d], W2r[dout][tap*128+c]
__global__ void repack_kernel(const float* __restrict__ W1, const float* __restrict__ W2,
                              unsigned short* __restrict__ W1r, unsigned short* __restrict__ W2r) {
    int i = blockIdx.x * 256 + threadIdx.x;
    if (i < C_ * K1) {
        int c = i / K1, k = i % K1;
        int tap = k >> 8, d = k & 255;
        int dt = tap / 3, dp = tap % 3;
        W1r[i] = f2bf(W1[((c * D_ + d) * 3 + dt) * 3 + dp]);
    } else {
        int i2 = i - C_ * K1;
        if (i2 < D_ * K2) {
            int dout = i2 / K2, k = i2 % K2;
            int tap = k >> 7, cc = k & 127;
            int dt = tap / 3, dp = tap % 3;
            W2r[i2] = f2bf(W2[((dout * C_ + cc) * 3 + dt) * 3 + dp]);
        }
    }
}

// ---- 4. DFT magnitude^2 (double accumulate) ----
__global__ void dft_kernel(const float* __restrict__ series, const double* __restrict__ tw,
                           float* __restrict__ mag2) {
    int bk = blockIdx.x;
    int k = bk % 513, b = bk / 513;
    int lane = threadIdx.x;
    const float* s = series + (size_t)b * L_;
    double re = 0.0, im = 0.0;
    #pragma unroll 4
    for (int i = 0; i < 16; i++) {
        int l = lane + 64 * i;
        int idx = (k * l) & 1023;
        double sv = (double)s[l];
        re += sv * tw[2 * idx];
        im += sv * tw[2 * idx + 1];
    }
    #pragma unroll
    for (int d = 32; d; d >>= 1) { re += __shfl_down(re, d); im += __shfl_down(im, d); }
    if (lane == 0) mag2[bk] = (k == 0) ? 0.0f : (float)(re * re + im * im);
}

// ---- 5. top-3 (tie -> lowest index, matching lax.top_k) ----
__global__ void topk_kernel(const float* __restrict__ mag2, int* __restrict__ periods) {
    int b = threadIdx.x;
    if (b >= B_) return;
    const float* m = mag2 + b * 513;
    int s0 = -1, s1 = -1;
    for (int j = 0; j < 3; j++) {
        float best = -1.0f; int bi = 0;
        for (int k = 0; k < 513; k++) {
            if (k == s0 || k == s1) continue;
            float v = m[k];
            if (v > best) { best = v; bi = k; }
        }
        if (j == 0) s0 = bi; else if (j == 1) s1 = bi;
        periods[b * 3 + j] = bi + 1;
    }
}

// ---- 6. conv1 (256->128) + bias + GELU, output col-major bf16 ----
// grid: b(64) x j(3) x tile(24 of 64 cols); block 256 = 4 waves (2x2)
__global__ __launch_bounds__(256)
void conv1_kernel(const unsigned short* __restrict__ xb,
                  const unsigned short* __restrict__ W1r,
                  const float* __restrict__ b1,
                  const int* __restrict__ periods,
                  unsigned short* __restrict__ out1g) {
    int blk = blockIdx.x;
    int tile = blk % 24;
    int bj = blk / 24;
    int j = bj % 3, b = bj / 3;
    int p = periods[b * 3 + j];
    if (p <= 1) return;
    int T = (L_ + p - 1) / p;
    int Lp = T * p;
    int col0 = tile * 64;
    if (col0 >= Lp) return;

    int tid = threadIdx.x;
    int w = tid >> 6, lane = tid & 63;
    int wm = w >> 1, wn = w & 1;
    int l15 = lane & 15, l4 = lane >> 4;

    int cols[2], ppv[2], ttv[2];
    #pragma unroll
    for (int nf = 0; nf < 2; nf++) {
        int c = col0 + wn * 32 + nf * 16 + l15;
        cols[nf] = c;
        ppv[nf] = c % p;
        ttv[nf] = c / p;
    }

    f32x4 acc[4][2];
    #pragma unroll
    for (int i = 0; i < 4; i++)
        #pragma unroll
        for (int nf = 0; nf < 2; nf++)
            acc[i][nf] = f32x4{0.f, 0.f, 0.f, 0.f};

    const unsigned short* xbb = xb + (size_t)b * L_ * D_ + 8 * l4;
    const unsigned short* w1b = W1r + 8 * l4;
    int rowb = wm * 64 + l15;

    #pragma unroll
    for (int tap = 0; tap < 9; tap++) {
        const int dt = tap / 3, dp = tap % 3;
        int off = (dt - 1) * p + (dp - 1);
        bool okl[2]; int tc[2];
        #pragma unroll
        for (int nf = 0; nf < 2; nf++) {
            bool ok = (ppv[nf] + dp >= 1) && (ppv[nf] + dp <= p) &&
                      (ttv[nf] + dt >= 1) && (ttv[nf] + dt <= T) && (cols[nf] < Lp);
            int t = cols[nf] + off;
            okl[nf] = ok && (t < L_);
            tc[nf] = t;
        }
        #pragma unroll
        for (int kk = 0; kk < 8; kk++) {
            bf16x8 A[4];
            #pragma unroll
            for (int i = 0; i < 4; i++)
                A[i] = ldg_bf16x8(w1b + (size_t)(rowb + i * 16) * K1 + tap * 256 + kk * 32);
            bf16x8 Bf[2];
            #pragma unroll
            for (int nf = 0; nf < 2; nf++)
                Bf[nf] = okl[nf] ? ldg_bf16x8(xbb + (size_t)tc[nf] * D_ + kk * 32) : zero_bf16x8();
            #pragma unroll
            for (int i = 0; i < 4; i++)
                #pragma unroll
                for (int nf = 0; nf < 2; nf++)
                    acc[i][nf] = __builtin_amdgcn_mfma_f32_16x16x32_bf16(A[i], Bf[nf], acc[i][nf], 0, 0, 0);
        }
    }

    size_t ob = (size_t)(b * 3 + j) * LPMAX * C_;
    #pragma unroll
    for (int i = 0; i < 4; i++) {
        int cb = wm * 64 + i * 16 + l4 * 4;
        float4 bias = *reinterpret_cast<const float4*>(b1 + cb);
        #pragma unroll
        for (int nf = 0; nf < 2; nf++) {
            if (cols[nf] < Lp) {
                ushort4 o;
                o.x = f2bf(gelu_exact(acc[i][nf][0] + bias.x));
                o.y = f2bf(gelu_exact(acc[i][nf][1] + bias.y));
                o.z = f2bf(gelu_exact(acc[i][nf][2] + bias.z));
                o.w = f2bf(gelu_exact(acc[i][nf][3] + bias.w));
                *reinterpret_cast<ushort4*>(out1g + ob + (size_t)cols[nf] * C_ + cb) = o;
            }
        }
    }
}

// ---- 7. conv2 (128->256) summed over 3 periods + residual; writes y to d_out ----
// grid: b(64) x tile(16 of 64 cols); block 256 = 4 waves (2x2); M=256
__global__ __launch_bounds__(256)
void conv2_kernel(const unsigned short* __restrict__ out1g,
                  const unsigned short* __restrict__ W2r,
                  const float* __restrict__ b2,
                  const int* __restrict__ periods,
                  const float* __restrict__ x,
                  float* __restrict__ yout) {
    int blk = blockIdx.x;
    int tile = blk & 15, b = blk >> 4;
    int tid = threadIdx.x;
    int w = tid >> 6, lane = tid & 63;
    int wm = w >> 1, wn = w & 1;
    int l15 = lane & 15, l4 = lane >> 4;

    int cols[2];
    #pragma unroll
    for (int nf = 0; nf < 2; nf++)
        cols[nf] = tile * 64 + wn * 32 + nf * 16 + l15;

    f32x4 acc[8][2];
    #pragma unroll
    for (int i = 0; i < 8; i++)
        #pragma unroll
        for (int nf = 0; nf < 2; nf++)
            acc[i][nf] = f32x4{0.f, 0.f, 0.f, 0.f};

    int nv = 0;
    for (int j = 0; j < 3; j++) {
        int p = periods[b * 3 + j];
        if (p <= 1) continue;
        nv++;
        int T = (L_ + p - 1) / p;
        int ppv[2], ttv[2];
        #pragma unroll
        for (int nf = 0; nf < 2; nf++) { ppv[nf] = cols[nf] % p; ttv[nf] = cols[nf] / p; }
        const unsigned short* base1 = out1g + (size_t)(b * 3 + j) * LPMAX * C_ + 8 * l4;

        #pragma unroll
        for (int tap = 0; tap < 9; tap++) {
            const int dt = tap / 3, dp = tap % 3;
            int off = (dt - 1) * p + (dp - 1);
            bool okl[2]; int tc[2];
            #pragma unroll
            for (int nf = 0; nf < 2; nf++) {
                okl[nf] = (ppv[nf] + dp >= 1) && (ppv[nf] + dp <= p) &&
                          (ttv[nf] + dt >= 1) && (ttv[nf] + dt <= T);
                tc[nf] = cols[nf] + off;
            }
            #pragma unroll
            for (int kk = 0; kk < 4; kk++) {
                bf16x8 A[8];
                #pragma unroll
                for (int i = 0; i < 8; i++)
                    A[i] = ldg_bf16x8(W2r + (size_t)(wm * 128 + i * 16 + l15) * K2 + tap * 128 + kk * 32 + 8 * l4);
                bf16x8 Bf[2];
                #pragma unroll
                for (int nf = 0; nf < 2; nf++)
                    Bf[nf] = okl[nf] ? ldg_bf16x8(base1 + (size_t)tc[nf] * C_ + kk * 32) : zero_bf16x8();
                #pragma unroll
                for (int i = 0; i < 8; i++)
                    #pragma unroll
                    for (int nf = 0; nf < 2; nf++)
                        acc[i][nf] = __builtin_amdgcn_mfma_f32_16x16x32_bf16(A[i], Bf[nf], acc[i][nf], 0, 0, 0);
            }
        }
    }

    const float inv3 = 1.0f / 3.0f;
    float fnv = (float)nv;
    #pragma unroll
    for (int i = 0; i < 8; i++) {
        int db = wm * 128 + i * 16 + l4 * 4;
        float4 bb = *reinterpret_cast<const float4*>(b2 + db);
        #pragma unroll
        for (int nf = 0; nf < 2; nf++) {
            size_t xoff = ((size_t)b * L_ + cols[nf]) * D_ + db;
            float4 xr = *reinterpret_cast<const float4*>(x + xoff);
            float4 o;
            o.x = xr.x + (acc[i][nf][0] + fnv * bb.x) * inv3;
            o.y = xr.y + (acc[i][nf][1] + fnv * bb.y) * inv3;
            o.z = xr.z + (acc[i][nf][2] + fnv * bb.z) * inv3;
            o.w = xr.w + (acc[i][nf][3] + fnv * bb.w) * inv3;
            *reinterpret_cast<float4*>(yout + xoff) = o;
        }
    }
}

// ---- 8. LayerNorm in-place on d_out ----
__global__ void ln_kernel(float* __restrict__ y, const float* __restrict__ gamma,
                          const float* __restrict__ beta) {
    int row = blockIdx.x * 4 + (threadIdx.x >> 6);
    int lane = threadIdx.x & 63;
    size_t base = (size_t)row * D_ + lane * 4;
    float4 v = *reinterpret_cast<const float4*>(y + base);
    float s = v.x + v.y + v.z + v.w;
    float s2 = v.x * v.x + v.y * v.y + v.z * v.z + v.w * v.w;
    #pragma unroll
    for (int d = 32; d; d >>= 1) { s += __shfl_xor(s, d); s2 += __shfl_xor(s2, d); }
    float mu = s * (1.0f / D_);
    float var = s2 * (1.0f / D_) - mu * mu;
    float inv = 1.0f / sqrtf(var + 1e-5f);
    float4 g = *reinterpret_cast<const float4*>(gamma + lane * 4);
    float4 be = *reinterpret_cast<const float4*>(beta + lane * 4);
    float4 o;
    o.x = (v.x - mu) * inv * g.x + be.x;
    o.y = (v.y - mu) * inv * g.y + be.y;
    o.z = (v.z - mu) * inv * g.z + be.z;
    o.w = (v.w - mu) * inv * g.w + be.w;
    *reinterpret_cast<float4*>(y + base) = o;
}

extern "C" void kernel_launch(void* const* d_in, const int* in_sizes, int n_in,
                              void* d_out, int out_size, void* d_ws, size_t ws_size,
                              hipStream_t stream) {
    const float* x     = (const float*)d_in[0];
    const float* W1    = (const float*)d_in[1];
    const float* b1    = (const float*)d_in[2];
    const float* W2    = (const float*)d_in[3];
    const float* b2    = (const float*)d_in[4];
    const float* gamma = (const float*)d_in[5];
    const float* beta  = (const float*)d_in[6];
    float* out = (float*)d_out;

    char* ws = (char*)d_ws;
    size_t off = 0;
    auto walloc = [&](size_t bytes) -> void* {
        void* pp = ws + off;
        off += (bytes + 255) & ~(size_t)255;
        return pp;
    };
    unsigned short* xb    = (unsigned short*)walloc((size_t)B_ * L_ * D_ * 2);
    unsigned short* out1g = (unsigned short*)walloc((size_t)B_ * 3 * LPMAX * C_ * 2);
    float* series         = (float*)walloc((size_t)B_ * L_ * 4);
    float* mag2           = (float*)walloc((size_t)B_ * 513 * 4);
    int* periods          = (int*)walloc((size_t)B_ * 3 * 4);
    double* tw            = (double*)walloc(1024 * 16);
    unsigned short* W1r   = (unsigned short*)walloc((size_t)C_ * K1 * 2);
    unsigned short* W2r   = (unsigned short*)walloc((size_t)D_ * K2 * 2);

    prep_kernel<<<B_ * L_ / 4, 256, 0, stream>>>(x, xb, series);
    tw_kernel<<<4, 256, 0, stream>>>(tw);
    repack_kernel<<<(C_ * K1 + D_ * K2 + 255) / 256, 256, 0, stream>>>(W1, W2, W1r, W2r);
    dft_kernel<<<B_ * 513, 64, 0, stream>>>(series, tw, mag2);
    topk_kernel<<<1, 64, 0, stream>>>(mag2, periods);
    conv1_kernel<<<B_ * 3 * 24, 256, 0, stream>>>(xb, W1r, b1, periods, out1g);
    conv2_kernel<<<B_ * 16, 256, 0, stream>>>(out1g, W2r, b2, periods, x, out);
    ln_kernel<<<B_ * L_ / 4, 256, 0, stream>>>(out, gamma, beta);
}

// Round 2
// 775.894 us; speedup vs baseline: 2.1310x; 2.1310x over previous
//
#include <hip/hip_runtime.h>
#include <hip/hip_bf16.h>
#include <math.h>

#define B_ 64
#define L_ 1024
#define D_ 256
#define C_ 128
#define LPMAX 1536
#define K1 2304   // 9 taps * 256
#define K2 1152   // 9 taps * 128

typedef __bf16 bf16x8 __attribute__((ext_vector_type(8)));
typedef float f32x4 __attribute__((ext_vector_type(4)));

__device__ __forceinline__ unsigned short f2bf(float f) {
    __hip_bfloat16 h = __float2bfloat16(f);
    return __builtin_bit_cast(unsigned short, h);
}

__device__ __forceinline__ bf16x8 zero_bf16x8() {
    uint4 z = {0u, 0u, 0u, 0u};
    return __builtin_bit_cast(bf16x8, z);
}

__device__ __forceinline__ float gelu_exact(float f) {
    return 0.5f * f * (1.0f + erff(f * 0.70710678118654752440f));
}

// async global->LDS, 16B per lane; LDS dest = wave-uniform base + lane*16
__device__ __forceinline__ void gl16(const unsigned short* g, unsigned short* l) {
    __builtin_amdgcn_global_load_lds(
        (const __attribute__((address_space(1))) unsigned int*)g,
        (__attribute__((address_space(3))) unsigned int*)l, 16, 0, 0);
}

// ---- 1. cast x to bf16 + channel-mean series ----
__global__ void prep_kernel(const float* __restrict__ x, unsigned short* __restrict__ xb,
                            float* __restrict__ series) {
    int row = blockIdx.x * 4 + (threadIdx.x >> 6);
    int lane = threadIdx.x & 63;
    size_t base = (size_t)row * D_ + lane * 4;
    float4 v = *reinterpret_cast<const float4*>(x + base);
    ushort4 o;
    o.x = f2bf(v.x); o.y = f2bf(v.y); o.z = f2bf(v.z); o.w = f2bf(v.w);
    *reinterpret_cast<ushort4*>(xb + base) = o;
    float s = v.x + v.y + v.z + v.w;
    #pragma unroll
    for (int d = 32; d; d >>= 1) s += __shfl_xor(s, d);
    if (lane == 0) series[row] = s * (1.0f / D_);
}

// ---- 2. twiddle table (double) ----
__global__ void tw_kernel(double* __restrict__ tw) {
    int j = blockIdx.x * 256 + threadIdx.x;
    if (j < 1024) {
        double a = -2.0 * 3.14159265358979323846 * (double)j / 1024.0;
        tw[2 * j] = cos(a);
        tw[2 * j + 1] = sin(a);
    }
}

// ---- 3. repack weights to bf16 GEMM layout ----
// W1r[c][tap*256+d], W2r[dout][tap*128+c]
__global__ void repack_kernel(const float* __restrict__ W1, const float* __restrict__ W2,
                              unsigned short* __restrict__ W1r, unsigned short* __restrict__ W2r) {
    int i = blockIdx.x * 256 + threadIdx.x;
    if (i < C_ * K1) {
        int c = i / K1, k = i % K1;
        int tap = k >> 8, d = k & 255;
        int dt = tap / 3, dp = tap % 3;
        W1r[i] = f2bf(W1[((c * D_ + d) * 3 + dt) * 3 + dp]);
    } else {
        int i2 = i - C_ * K1;
        if (i2 < D_ * K2) {
            int dout = i2 / K2, k = i2 % K2;
            int tap = k >> 7, cc = k & 127;
            int dt = tap / 3, dp = tap % 3;
            W2r[i2] = f2bf(W2[((dout * C_ + cc) * 3 + dt) * 3 + dp]);
        }
    }
}

// ---- 4. DFT magnitude^2 (double accumulate) ----
__global__ void dft_kernel(const float* __restrict__ series, const double* __restrict__ tw,
                           float* __restrict__ mag2) {
    int bk = blockIdx.x;
    int k = bk % 513, b = bk / 513;
    int lane = threadIdx.x;
    const float* s = series + (size_t)b * L_;
    double re = 0.0, im = 0.0;
    #pragma unroll 4
    for (int i = 0; i < 16; i++) {
        int l = lane + 64 * i;
        int idx = (k * l) & 1023;
        double sv = (double)s[l];
        re += sv * tw[2 * idx];
        im += sv * tw[2 * idx + 1];
    }
    #pragma unroll
    for (int d = 32; d; d >>= 1) { re += __shfl_down(re, d); im += __shfl_down(im, d); }
    if (lane == 0) mag2[bk] = (k == 0) ? 0.0f : (float)(re * re + im * im);
}

// ---- 5. top-3 (tie -> lowest index, matching lax.top_k) ----
__global__ void topk_kernel(const float* __restrict__ mag2, int* __restrict__ periods) {
    int b = threadIdx.x;
    if (b >= B_) return;
    const float* m = mag2 + b * 513;
    int s0 = -1, s1 = -1;
    for (int j = 0; j < 3; j++) {
        float best = -1.0f; int bi = 0;
        for (int k = 0; k < 513; k++) {
            if (k == s0 || k == s1) continue;
            float v = m[k];
            if (v > best) { best = v; bi = k; }
        }
        if (j == 0) s0 = bi; else if (j == 1) s1 = bi;
        periods[b * 3 + j] = bi + 1;
    }
}

// ---- 6. conv1 (256->128) + bias + GELU, output col-major bf16 ----
// 128x128 tile, BK=64, 4 waves 2x2, double-buffered LDS via global_load_lds
__global__ __launch_bounds__(256)
void conv1_kernel(const unsigned short* __restrict__ xb,
                  const unsigned short* __restrict__ W1r,
                  const float* __restrict__ b1,
                  const int* __restrict__ periods,
                  unsigned short* __restrict__ out1g) {
    __shared__ __align__(16) unsigned short lA[2][128 * 64];
    __shared__ __align__(16) unsigned short lB[2][128 * 64];

    const int blk = blockIdx.x;
    const int tile = blk % 12;
    const int bj = blk / 12;
    const int j = bj % 3, b = bj / 3;
    const int p = periods[b * 3 + j];
    if (p <= 1) return;
    const int T = (L_ + p - 1) / p;
    const int Lp = T * p;
    const int col0 = tile * 128;
    if (col0 >= Lp) return;

    const int tid = threadIdx.x;
    const int w = tid >> 6, lane = tid & 63;
    const int wm = w >> 1, wn = w & 1;
    const int l15 = lane & 15, l4 = lane >> 4;
    const int l8 = lane >> 3, l7 = lane & 7;
    const int swz8 = (l7 ^ l8) * 8;   // staging source chunk swizzle (ushort units)

    const unsigned short* xbb = xb + (size_t)b * L_ * D_;

    const unsigned short* asrc[4];
    int stcol[4];
    #pragma unroll
    for (int q = 0; q < 4; q++) {
        int r = w * 32 + q * 8 + l8;
        asrc[q] = W1r + (size_t)r * K1 + swz8;
        stcol[q] = col0 + r;
    }

    int cols[4], ppv[4], ttv[4];
    #pragma unroll
    for (int nf = 0; nf < 4; nf++) {
        cols[nf] = col0 + wn * 64 + nf * 16 + l15;
        ppv[nf] = cols[nf] % p;
        ttv[nf] = cols[nf] / p;
    }

    int offA[2][4], offB[2][4];
    #pragma unroll
    for (int kk = 0; kk < 2; kk++) {
        int cswz = ((4 * kk + l4) ^ (l15 & 7)) * 8;
        #pragma unroll
        for (int i = 0; i < 4; i++) offA[kk][i] = (wm * 64 + i * 16 + l15) * 64 + cswz;
        #pragma unroll
        for (int nf = 0; nf < 4; nf++) offB[kk][nf] = (wn * 64 + nf * 16 + l15) * 64 + cswz;
    }

    f32x4 acc[4][4];
    #pragma unroll
    for (int i = 0; i < 4; i++)
        #pragma unroll
        for (int nf = 0; nf < 4; nf++)
            acc[i][nf] = f32x4{0.f, 0.f, 0.f, 0.f};

    auto stage = [&](int buf, int ks) {
        int tap = ks >> 2, kk0 = (ks & 3) * 64;
        int dt3 = tap / 3, dp3 = tap - 3 * dt3;
        int off = (dt3 - 1) * p + (dp3 - 1);
        int koff = tap * 256 + kk0;
        unsigned short* la = lA[buf];
        unsigned short* lb = lB[buf];
        #pragma unroll
        for (int q = 0; q < 4; q++)
            gl16(asrc[q] + koff, la + (w * 32 + q * 8) * 64);
        #pragma unroll
        for (int q = 0; q < 4; q++) {
            int tc = stcol[q] + off;
            tc = tc < 0 ? 0 : (tc > L_ - 1 ? L_ - 1 : tc);
            gl16(xbb + (size_t)tc * D_ + kk0 + swz8, lb + (w * 32 + q * 8) * 64);
        }
    };

    stage(0, 0);
    __syncthreads();

    const int NK = 36;
    for (int ks = 0; ks < NK; ks++) {
        const int cur = ks & 1;
        if (ks + 1 < NK) stage(cur ^ 1, ks + 1);

        const int tap = ks >> 2;
        const int dt3 = tap / 3, dp3 = tap - 3 * dt3;
        const int off = (dt3 - 1) * p + (dp3 - 1);
        bool ok[4];
        #pragma unroll
        for (int nf = 0; nf < 4; nf++) {
            int pd = ppv[nf] + dp3, td = ttv[nf] + dt3;
            int t = cols[nf] + off;
            ok[nf] = (pd >= 1) && (pd <= p) && (td >= 1) && (td <= T) &&
                     (cols[nf] < Lp) && (t < L_);
        }
        const unsigned short* la = lA[cur];
        const unsigned short* lb = lB[cur];
        #pragma unroll
        for (int kk = 0; kk < 2; kk++) {
            bf16x8 Af[4], Bf[4];
            #pragma unroll
            for (int i = 0; i < 4; i++)
                Af[i] = *reinterpret_cast<const bf16x8*>(la + offA[kk][i]);
            #pragma unroll
            for (int nf = 0; nf < 4; nf++) {
                Bf[nf] = *reinterpret_cast<const bf16x8*>(lb + offB[kk][nf]);
                if (!ok[nf]) Bf[nf] = zero_bf16x8();
            }
            #pragma unroll
            for (int i = 0; i < 4; i++)
                #pragma unroll
                for (int nf = 0; nf < 4; nf++)
                    acc[i][nf] = __builtin_amdgcn_mfma_f32_16x16x32_bf16(Af[i], Bf[nf], acc[i][nf], 0, 0, 0);
        }
        __syncthreads();
    }

    const size_t ob = (size_t)(b * 3 + j) * LPMAX * C_;
    #pragma unroll
    for (int i = 0; i < 4; i++) {
        const int ch = wm * 64 + i * 16 + l4 * 4;
        const float4 bias = *reinterpret_cast<const float4*>(b1 + ch);
        #pragma unroll
        for (int nf = 0; nf < 4; nf++) {
            const int c = cols[nf];
            if (c < Lp) {
                ushort4 o;
                o.x = f2bf(gelu_exact(acc[i][nf][0] + bias.x));
                o.y = f2bf(gelu_exact(acc[i][nf][1] + bias.y));
                o.z = f2bf(gelu_exact(acc[i][nf][2] + bias.z));
                o.w = f2bf(gelu_exact(acc[i][nf][3] + bias.w));
                *reinterpret_cast<ushort4*>(out1g + ob + (size_t)c * C_ + ch) = o;
            }
        }
    }
}

// ---- 7. conv2 (128->256) summed over 3 periods + residual; writes y to d_out ----
// 128x128 tile (M split in halves), BK=64, 4 waves 2x2, double-buffered LDS
__global__ __launch_bounds__(256)
void conv2_kernel(const unsigned short* __restrict__ out1g,
                  const unsigned short* __restrict__ W2r,
                  const float* __restrict__ b2,
                  const int* __restrict__ periods,
                  const float* __restrict__ x,
                  float* __restrict__ yout) {
    __shared__ __align__(16) unsigned short lA[2][128 * 64];
    __shared__ __align__(16) unsigned short lB[2][128 * 64];

    const int blk = blockIdx.x;
    const int mhalf = blk & 1;
    const int tile = (blk >> 1) & 7;
    const int b = blk >> 4;

    const int p0 = periods[b * 3 + 0], p1 = periods[b * 3 + 1], p2 = periods[b * 3 + 2];
    const int T0 = (L_ + p0 - 1) / p0, T1 = (L_ + p1 - 1) / p1, T2 = (L_ + p2 - 1) / p2;
    const int nv = (p0 > 1) + (p1 > 1) + (p2 > 1);

    const int tid = threadIdx.x;
    const int w = tid >> 6, lane = tid & 63;
    const int wm = w >> 1, wn = w & 1;
    const int l15 = lane & 15, l4 = lane >> 4;
    const int l8 = lane >> 3, l7 = lane & 7;
    const int swz8 = (l7 ^ l8) * 8;
    const int col0 = tile * 128;

    const unsigned short* asrc[4];
    int stcol[4];
    #pragma unroll
    for (int q = 0; q < 4; q++) {
        int r = w * 32 + q * 8 + l8;
        asrc[q] = W2r + (size_t)(mhalf * 128 + r) * K2 + swz8;
        stcol[q] = col0 + r;
    }

    const unsigned short* o1b0 = out1g + (size_t)(b * 3 + 0) * LPMAX * C_;
    const unsigned short* o1b1 = out1g + (size_t)(b * 3 + 1) * LPMAX * C_;
    const unsigned short* o1b2 = out1g + (size_t)(b * 3 + 2) * LPMAX * C_;

    int cols[4];
    int pv0[4], tv0[4], pv1[4], tv1[4], pv2[4], tv2[4];
    #pragma unroll
    for (int nf = 0; nf < 4; nf++) {
        cols[nf] = col0 + wn * 64 + nf * 16 + l15;
        pv0[nf] = cols[nf] % p0; tv0[nf] = cols[nf] / p0;
        pv1[nf] = cols[nf] % p1; tv1[nf] = cols[nf] / p1;
        pv2[nf] = cols[nf] % p2; tv2[nf] = cols[nf] / p2;
    }

    int offA[2][4], offB[2][4];
    #pragma unroll
    for (int kk = 0; kk < 2; kk++) {
        int cswz = ((4 * kk + l4) ^ (l15 & 7)) * 8;
        #pragma unroll
        for (int i = 0; i < 4; i++) offA[kk][i] = (wm * 64 + i * 16 + l15) * 64 + cswz;
        #pragma unroll
        for (int nf = 0; nf < 4; nf++) offB[kk][nf] = (wn * 64 + nf * 16 + l15) * 64 + cswz;
    }

    f32x4 acc[4][4];
    #pragma unroll
    for (int i = 0; i < 4; i++)
        #pragma unroll
        for (int nf = 0; nf < 4; nf++)
            acc[i][nf] = f32x4{0.f, 0.f, 0.f, 0.f};

    auto stage = [&](int buf, int ks) {
        int jn = ks / 18, rem = ks - jn * 18;
        int tap = rem >> 1, kk0 = (rem & 1) * 64;
        int dt3 = tap / 3, dp3 = tap - 3 * dt3;
        int pj = (jn == 0) ? p0 : ((jn == 1) ? p1 : p2);
        const unsigned short* bb = (jn == 0) ? o1b0 : ((jn == 1) ? o1b1 : o1b2);
        int off = (dt3 - 1) * pj + (dp3 - 1);
        int koff = tap * 128 + kk0;
        unsigned short* la = lA[buf];
        unsigned short* lb = lB[buf];
        #pragma unroll
        for (int q = 0; q < 4; q++)
            gl16(asrc[q] + koff, la + (w * 32 + q * 8) * 64);
        #pragma unroll
        for (int q = 0; q < 4; q++) {
            int tc = stcol[q] + off;
            tc = tc < 0 ? 0 : (tc > LPMAX - 1 ? LPMAX - 1 : tc);
            gl16(bb + (size_t)tc * C_ + kk0 + swz8, lb + (w * 32 + q * 8) * 64);
        }
    };

    stage(0, 0);
    __syncthreads();

    const int NK = 54;
    for (int ks = 0; ks < NK; ks++) {
        const int cur = ks & 1;
        if (ks + 1 < NK) stage(cur ^ 1, ks + 1);

        const int jn = ks / 18, rem = ks - jn * 18;
        const int tap = rem >> 1;
        const int dt3 = tap / 3, dp3 = tap - 3 * dt3;
        const int pj = (jn == 0) ? p0 : ((jn == 1) ? p1 : p2);
        const int Tj = (jn == 0) ? T0 : ((jn == 1) ? T1 : T2);
        bool ok[4];
        #pragma unroll
        for (int nf = 0; nf < 4; nf++) {
            int pv = (jn == 0) ? pv0[nf] : ((jn == 1) ? pv1[nf] : pv2[nf]);
            int tv = (jn == 0) ? tv0[nf] : ((jn == 1) ? tv1[nf] : tv2[nf]);
            int pd = pv + dp3, td = tv + dt3;
            ok[nf] = (pj > 1) && (pd >= 1) && (pd <= pj) && (td >= 1) && (td <= Tj);
        }
        const unsigned short* la = lA[cur];
        const unsigned short* lb = lB[cur];
        #pragma unroll
        for (int kk = 0; kk < 2; kk++) {
            bf16x8 Af[4], Bf[4];
            #pragma unroll
            for (int i = 0; i < 4; i++)
                Af[i] = *reinterpret_cast<const bf16x8*>(la + offA[kk][i]);
            #pragma unroll
            for (int nf = 0; nf < 4; nf++) {
                Bf[nf] = *reinterpret_cast<const bf16x8*>(lb + offB[kk][nf]);
                if (!ok[nf]) Bf[nf] = zero_bf16x8();
            }
            #pragma unroll
            for (int i = 0; i < 4; i++)
                #pragma unroll
                for (int nf = 0; nf < 4; nf++)
                    acc[i][nf] = __builtin_amdgcn_mfma_f32_16x16x32_bf16(Af[i], Bf[nf], acc[i][nf], 0, 0, 0);
        }
        __syncthreads();
    }

    const float inv3 = 1.0f / 3.0f;
    const float fnv = (float)nv;
    #pragma unroll
    for (int i = 0; i < 4; i++) {
        const int dout = mhalf * 128 + wm * 64 + i * 16 + l4 * 4;
        const float4 bb = *reinterpret_cast<const float4*>(b2 + dout);
        #pragma unroll
        for (int nf = 0; nf < 4; nf++) {
            const size_t xoff = ((size_t)b * L_ + cols[nf]) * D_ + dout;
            const float4 xr = *reinterpret_cast<const float4*>(x + xoff);
            float4 o;
            o.x = xr.x + (acc[i][nf][0] + fnv * bb.x) * inv3;
            o.y = xr.y + (acc[i][nf][1] + fnv * bb.y) * inv3;
            o.z = xr.z + (acc[i][nf][2] + fnv * bb.z) * inv3;
            o.w = xr.w + (acc[i][nf][3] + fnv * bb.w) * inv3;
            *reinterpret_cast<float4*>(yout + xoff) = o;
        }
    }
}

// ---- 8. LayerNorm in-place on d_out ----
__global__ void ln_kernel(float* __restrict__ y, const float* __restrict__ gamma,
                          const float* __restrict__ beta) {
    int row = blockIdx.x * 4 + (threadIdx.x >> 6);
    int lane = threadIdx.x & 63;
    size_t base = (size_t)row * D_ + lane * 4;
    float4 v = *reinterpret_cast<const float4*>(y + base);
    float s = v.x + v.y + v.z + v.w;
    float s2 = v.x * v.x + v.y * v.y + v.z * v.z + v.w * v.w;
    #pragma unroll
    for (int d = 32; d; d >>= 1) { s += __shfl_xor(s, d); s2 += __shfl_xor(s2, d); }
    float mu = s * (1.0f / D_);
    float var = s2 * (1.0f / D_) - mu * mu;
    float inv = 1.0f / sqrtf(var + 1e-5f);
    float4 g = *reinterpret_cast<const float4*>(gamma + lane * 4);
    float4 be = *reinterpret_cast<const float4*>(beta + lane * 4);
    float4 o;
    o.x = (v.x - mu) * inv * g.x + be.x;
    o.y = (v.y - mu) * inv * g.y + be.y;
    o.z = (v.z - mu) * inv * g.z + be.z;
    o.w = (v.w - mu) * inv * g.w + be.w;
    *reinterpret_cast<float4*>(y + base) = o;
}

extern "C" void kernel_launch(void* const* d_in, const int* in_sizes, int n_in,
                              void* d_out, int out_size, void* d_ws, size_t ws_size,
                              hipStream_t stream) {
    const float* x     = (const float*)d_in[0];
    const float* W1    = (const float*)d_in[1];
    const float* b1    = (const float*)d_in[2];
    const float* W2    = (const float*)d_in[3];
    const float* b2    = (const float*)d_in[4];
    const float* gamma = (const float*)d_in[5];
    const float* beta  = (const float*)d_in[6];
    float* out = (float*)d_out;

    char* ws = (char*)d_ws;
    size_t off = 0;
    auto walloc = [&](size_t bytes) -> void* {
        void* pp = ws + off;
        off += (bytes + 255) & ~(size_t)255;
        return pp;
    };
    unsigned short* xb    = (unsigned short*)walloc((size_t)B_ * L_ * D_ * 2);
    unsigned short* out1g = (unsigned short*)walloc((size_t)B_ * 3 * LPMAX * C_ * 2);
    float* series         = (float*)walloc((size_t)B_ * L_ * 4);
    float* mag2           = (float*)walloc((size_t)B_ * 513 * 4);
    int* periods          = (int*)walloc((size_t)B_ * 3 * 4);
    double* tw            = (double*)walloc(1024 * 16);
    unsigned short* W1r   = (unsigned short*)walloc((size_t)C_ * K1 * 2);
    unsigned short* W2r   = (unsigned short*)walloc((size_t)D_ * K2 * 2);

    prep_kernel<<<B_ * L_ / 4, 256, 0, stream>>>(x, xb, series);
    tw_kernel<<<4, 256, 0, stream>>>(tw);
    repack_kernel<<<(C_ * K1 + D_ * K2 + 255) / 256, 256, 0, stream>>>(W1, W2, W1r, W2r);
    dft_kernel<<<B_ * 513, 64, 0, stream>>>(series, tw, mag2);
    topk_kernel<<<1, 64, 0, stream>>>(mag2, periods);
    conv1_kernel<<<B_ * 3 * 12, 256, 0, stream>>>(xb, W1r, b1, periods, out1g);
    conv2_kernel<<<B_ * 16, 256, 0, stream>>>(out1g, W2r, b2, periods, x, out);
    ln_kernel<<<B_ * L_ / 4, 256, 0, stream>>>(out, gamma, beta);
}